// Round 2
// baseline (490.106 us; speedup 1.0000x reference)
//
#include <hip/hip_runtime.h>
#include <hip/hip_bf16.h>
#include <cstdint>

typedef uint16_t u16;
typedef __attribute__((ext_vector_type(8))) __bf16 bf16x8;
typedef __attribute__((ext_vector_type(4))) float f32x4;

#define GLD_LDS(SRC, DST) \
  __builtin_amdgcn_global_load_lds((const __attribute__((address_space(1))) void*)(SRC), \
                                   (__attribute__((address_space(3))) void*)(DST), 16, 0, 0)

__device__ __forceinline__ u16 f2bf(float f) {
  uint32_t u = __float_as_uint(f);
  u += 0x7fffu + ((u >> 16) & 1u);   // RNE; inputs are finite
  return (u16)(u >> 16);
}

// ---------------- cast fp32 -> bf16, 4 elems/thread ----------------
__global__ void cast_f32_bf16(const float* __restrict__ in, u16* __restrict__ out, int n4) {
  int i = blockIdx.x * blockDim.x + threadIdx.x;
  if (i < n4) {
    const float4 v = reinterpret_cast<const float4*>(in)[i];
    ushort4 o;
    o.x = f2bf(v.x); o.y = f2bf(v.y); o.z = f2bf(v.z); o.w = f2bf(v.w);
    reinterpret_cast<ushort4*>(out)[i] = o;
  }
}

// ---------------- W[K][N] f32 -> Wt[N][K] bf16 ----------------
__global__ void transpose_cast(const float* __restrict__ W, u16* __restrict__ Wt, int K, int N) {
  __shared__ float tile[32][33];
  int n0 = blockIdx.x * 32, k0 = blockIdx.y * 32;
  int tx = threadIdx.x, ty = threadIdx.y;
  #pragma unroll
  for (int i = ty; i < 32; i += 8)
    tile[i][tx] = W[(size_t)(k0 + i) * N + n0 + tx];
  __syncthreads();
  #pragma unroll
  for (int i = ty; i < 32; i += 8)
    Wt[(size_t)(n0 + i) * K + k0 + tx] = f2bf(tile[tx][i]);
}

// ---------------- RoPE cos/sin tables [T][32] ----------------
__global__ void rope_tables_k(float* __restrict__ cosT, float* __restrict__ sinT) {
  int t = blockIdx.x, i = threadIdx.x;  // 32 threads
  float invf = powf(10000.0f, -(float)i * (1.0f / 32.0f));
  float ang = (float)t * invf;
  cosT[t * 32 + i] = cosf(ang);
  sinT[t * 32 + i] = sinf(ang);
}

// ---------------- GEMM: C[M][N] f32 = A[M][K]bf16 * Bt[N][K]bf16^T ----------------
// m97 structure: 128x128 tile, BK=32, 4 waves 2x2, global_load_lds width=16.
__global__ __launch_bounds__(256) void gemm_bt(const u16* __restrict__ A, const u16* __restrict__ Bt,
                                               float* __restrict__ C, int M, int N, int K) {
  __shared__ alignas(16) u16 As[128 * 32];
  __shared__ alignas(16) u16 Bs[128 * 32];
  int tid = threadIdx.x;
  int l = tid & 63, w = tid >> 6;
  int l15 = l & 15, l4 = l >> 4;
  int wr = w >> 1, wc = w & 1;
  int m0 = blockIdx.y * 128, n0 = blockIdx.x * 128;

  f32x4 acc[4][4] = {};

  int srow = tid >> 2;
  int scol = (tid & 3) * 8;
  const u16* Ag = A + (size_t)(m0 + srow) * K + scol;
  const u16* Bg = Bt + (size_t)(n0 + srow) * K + scol;
  char* AsD = (char*)As + tid * 16;
  char* BsD = (char*)Bs + tid * 16;
  const size_t rowskip = (size_t)64 * K;

  for (int kt = 0; kt < K; kt += 32) {
    GLD_LDS(Ag + kt, AsD);
    GLD_LDS(Ag + kt + rowskip, AsD + 4096);
    GLD_LDS(Bg + kt, BsD);
    GLD_LDS(Bg + kt + rowskip, BsD + 4096);
    __syncthreads();
    bf16x8 af[4], bfr[4];
    #pragma unroll
    for (int m = 0; m < 4; ++m)
      af[m] = *reinterpret_cast<const bf16x8*>(&As[(wr * 64 + m * 16 + l15) * 32 + l4 * 8]);
    #pragma unroll
    for (int n = 0; n < 4; ++n)
      bfr[n] = *reinterpret_cast<const bf16x8*>(&Bs[(wc * 64 + n * 16 + l15) * 32 + l4 * 8]);
    #pragma unroll
    for (int m = 0; m < 4; ++m)
      #pragma unroll
      for (int n = 0; n < 4; ++n)
        acc[m][n] = __builtin_amdgcn_mfma_f32_16x16x32_bf16(af[m], bfr[n], acc[m][n], 0, 0, 0);
    __syncthreads();
  }
  #pragma unroll
  for (int m = 0; m < 4; ++m)
    #pragma unroll
    for (int n = 0; n < 4; ++n)
      #pragma unroll
      for (int r = 0; r < 4; ++r) {
        int row = m0 + wr * 64 + m * 16 + l4 * 4 + r;
        int col = n0 + wc * 64 + n * 16 + l15;
        C[(size_t)row * N + col] = acc[m][n][r];
      }
}

// ---------------- RoPE + scatter ----------------
__global__ __launch_bounds__(256) void rope_scatter(const float* __restrict__ QKV,
    const float* __restrict__ cosT, const float* __restrict__ sinT,
    u16* __restrict__ Qr, u16* __restrict__ Kr, u16* __restrict__ Vb,
    float* __restrict__ outK, float* __restrict__ outV) {
  int row = blockIdx.x;            // b*2048 + t
  int b = row >> 11, t = row & 2047;
  const float* src = QKV + (size_t)row * 3072;
  int tid = threadIdx.x;
  #pragma unroll
  for (int p = tid; p < 1024; p += 256) {
    int h = p >> 5, d = p & 31;
    float c = cosT[t * 32 + d], s = sinT[t * 32 + d];
    float q0 = src[h * 64 + d], q1 = src[h * 64 + d + 32];
    size_t base = ((size_t)(b * 32 + h) * 2048 + t) * 64 + d;
    Qr[base]      = f2bf((q0 * c - q1 * s) * 0.125f);
    Qr[base + 32] = f2bf((q1 * c + q0 * s) * 0.125f);
  }
  {
    int p = tid;                    // exactly 256 (g,d) pairs
    int gk = p >> 5, d = p & 31;
    float c = cosT[t * 32 + d], s = sinT[t * 32 + d];
    float k0 = src[2048 + gk * 64 + d], k1 = src[2048 + gk * 64 + d + 32];
    float r0 = k0 * c - k1 * s, r1 = k1 * c + k0 * s;
    size_t base = ((size_t)(b * 8 + gk) * 2048 + t) * 64 + d;
    Kr[base] = f2bf(r0); Kr[base + 32] = f2bf(r1);
    outK[base] = r0; outK[base + 32] = r1;
  }
  #pragma unroll
  for (int p = tid; p < 512; p += 256) {
    int gv = p >> 6, d = p & 63;
    float v = src[2560 + gv * 64 + d];
    size_t base = ((size_t)(b * 8 + gv) * 2048 + t) * 64 + d;
    Vb[base] = f2bf(v);
    outV[base] = v;
  }
}

// ---------------- flash attention, causal GQA ----------------
// grid (qb=32, h=32, b=2), 256 thr = 4 waves x 16 q-rows. KVBLK=64.
__global__ __launch_bounds__(256) void attn_kernel(const u16* __restrict__ Qr,
    const u16* __restrict__ Kr, const u16* __restrict__ Vb, u16* __restrict__ Ao) {
  __shared__ alignas(16) u16 Ks[64][72];       // [kv][d], pitch 72
  __shared__ alignas(16) u16 VsT[64][72];      // [d][kv]
  __shared__ alignas(16) u16 Ps[4][16][72];    // per-wave P bounce

  int qb = blockIdx.x, h = blockIdx.y, b = blockIdx.z;
  int g = h >> 2;
  int tid = threadIdx.x, w = tid >> 6, l = tid & 63;
  int l15 = l & 15, l4 = l >> 4;

  const u16* Qh = Qr + ((size_t)(b * 32 + h) * 2048) * 64;
  const u16* Kh = Kr + ((size_t)(b * 8 + g) * 2048) * 64;
  const u16* Vh = Vb + ((size_t)(b * 8 + g) * 2048) * 64;

  int qrow0 = qb * 64 + w * 16;
  bf16x8 qf[2];
  #pragma unroll
  for (int kk = 0; kk < 2; ++kk)
    qf[kk] = *reinterpret_cast<const bf16x8*>(Qh + (size_t)(qrow0 + l15) * 64 + kk * 32 + l4 * 8);

  f32x4 o[4] = {};
  float mrow[4] = {-INFINITY, -INFINITY, -INFINITY, -INFINITY};
  float lrow[4] = {0.f, 0.f, 0.f, 0.f};

  int skv = tid >> 3, sd0 = (tid & 7) * 8;

  for (int s = 0; s <= qb; ++s) {
    #pragma unroll
    for (int p = 0; p < 2; ++p) {            // FIX: cover all 64 kv rows (was 32)
      int row = skv + p * 32;
      bf16x8 kvec = *reinterpret_cast<const bf16x8*>(Kh + (size_t)(s * 64 + row) * 64 + sd0);
      *reinterpret_cast<bf16x8*>(&Ks[row][sd0]) = kvec;
      union { bf16x8 v; u16 u[8]; } uv;
      uv.v = *reinterpret_cast<const bf16x8*>(Vh + (size_t)(s * 64 + row) * 64 + sd0);
      #pragma unroll
      for (int i = 0; i < 8; ++i) {          // rotated order -> fewer write conflicts
        int j = (i + (tid & 7)) & 7;
        VsT[sd0 + j][row] = uv.u[j];
      }
    }
    __syncthreads();

    f32x4 sf[4];
    #pragma unroll
    for (int nf = 0; nf < 4; ++nf) {
      f32x4 z = {};
      #pragma unroll
      for (int kk = 0; kk < 2; ++kk) {
        bf16x8 kf = *reinterpret_cast<const bf16x8*>(&Ks[nf * 16 + l15][kk * 32 + l4 * 8]);
        z = __builtin_amdgcn_mfma_f32_16x16x32_bf16(qf[kk], kf, z, 0, 0, 0);
      }
      sf[nf] = z;
    }
    if (s == qb) {
      #pragma unroll
      for (int nf = 0; nf < 4; ++nf)
        #pragma unroll
        for (int r = 0; r < 4; ++r) {
          int qrow = qrow0 + l4 * 4 + r;
          int kcol = s * 64 + nf * 16 + l15;
          if (kcol > qrow) sf[nf][r] = -1e30f;
        }
    }
    float pexp[4][4];
    #pragma unroll
    for (int r = 0; r < 4; ++r) {
      float mx = fmaxf(fmaxf(sf[0][r], sf[1][r]), fmaxf(sf[2][r], sf[3][r]));
      #pragma unroll
      for (int off = 8; off >= 1; off >>= 1) mx = fmaxf(mx, __shfl_xor(mx, off, 16));
      float mnew = fmaxf(mrow[r], mx);
      float corr = __expf(mrow[r] - mnew);
      float ssum = 0.f;
      #pragma unroll
      for (int nf = 0; nf < 4; ++nf) {
        float p = __expf(sf[nf][r] - mnew);
        pexp[nf][r] = p;
        ssum += p;
      }
      #pragma unroll
      for (int off = 8; off >= 1; off >>= 1) ssum += __shfl_xor(ssum, off, 16);
      lrow[r] = lrow[r] * corr + ssum;
      mrow[r] = mnew;
      #pragma unroll
      for (int df = 0; df < 4; ++df) o[df][r] *= corr;
    }
    #pragma unroll
    for (int nf = 0; nf < 4; ++nf)
      #pragma unroll
      for (int r = 0; r < 4; ++r)
        Ps[w][l4 * 4 + r][nf * 16 + l15] = f2bf(pexp[nf][r]);
    #pragma unroll
    for (int df = 0; df < 4; ++df) {
      #pragma unroll
      for (int kk = 0; kk < 2; ++kk) {
        bf16x8 pf = *reinterpret_cast<const bf16x8*>(&Ps[w][l15][kk * 32 + l4 * 8]);
        bf16x8 vf = *reinterpret_cast<const bf16x8*>(&VsT[df * 16 + l15][kk * 32 + l4 * 8]);
        o[df] = __builtin_amdgcn_mfma_f32_16x16x32_bf16(pf, vf, o[df], 0, 0, 0);
      }
    }
    __syncthreads();
  }
  #pragma unroll
  for (int r = 0; r < 4; ++r) {
    float inv = 1.0f / lrow[r];
    int row = b * 2048 + qb * 64 + w * 16 + l4 * 4 + r;
    size_t base = (size_t)row * 2048 + h * 64;
    #pragma unroll
    for (int df = 0; df < 4; ++df)
      Ao[base + df * 16 + l15] = f2bf(o[df][r] * inv);
  }
}

extern "C" void kernel_launch(void* const* d_in, const int* in_sizes, int n_in,
                              void* d_out, int out_size, void* d_ws, size_t ws_size,
                              hipStream_t stream) {
  const float* x  = (const float*)d_in[0];
  const float* Wq = (const float*)d_in[1];
  const float* Wk = (const float*)d_in[2];
  const float* Wv = (const float*)d_in[3];
  const float* Wo = (const float*)d_in[4];
  float* out = (float*)d_out;

  // workspace carve (bytes), all 256-aligned; total ~113.8 MB
  char* ws = (char*)d_ws;
  u16*   Xb    = (u16*)(ws + 0);              // [4096][2048] bf16
  u16*   Wcat  = (u16*)(ws + 16777216);       // [3072][2048] bf16 = {Wq^T, Wk^T, Wv^T}
  u16*   WoT   = (u16*)(ws + 29360128);       // [2048][2048] bf16
  float* QKV   = (float*)(ws + 37748736);     // [4096][3072] f32
  u16*   AttnB = (u16*)(ws + 37748736);       // reuse after rope: [4096][2048] bf16
  u16*   Qr    = (u16*)(ws + 88080384);       // [2][32][2048][64] bf16 (pre-scaled)
  u16*   Kr    = (u16*)(ws + 104857600);      // [2][8][2048][64] bf16
  u16*   Vb    = (u16*)(ws + 109051904);      // [2][8][2048][64] bf16
  float* cosT  = (float*)(ws + 113246208);    // [2048][32]
  float* sinT  = (float*)(ws + 113508352);    // [2048][32]

  float* outK = out + 8388608;
  float* outV = out + 10485760;

  cast_f32_bf16<<<8192, 256, 0, stream>>>(x, Xb, 2097152);
  transpose_cast<<<dim3(64, 64), dim3(32, 8), 0, stream>>>(Wq, Wcat, 2048, 2048);
  transpose_cast<<<dim3(16, 64), dim3(32, 8), 0, stream>>>(Wk, Wcat + 2048 * 2048, 2048, 512);
  transpose_cast<<<dim3(16, 64), dim3(32, 8), 0, stream>>>(Wv, Wcat + 2560 * 2048, 2048, 512);
  transpose_cast<<<dim3(64, 64), dim3(32, 8), 0, stream>>>(Wo, WoT, 2048, 2048);
  rope_tables_k<<<2048, 32, 0, stream>>>(cosT, sinT);
  gemm_bt<<<dim3(24, 32), 256, 0, stream>>>(Xb, Wcat, QKV, 4096, 3072, 2048);
  rope_scatter<<<4096, 256, 0, stream>>>(QKV, cosT, sinT, Qr, Kr, Vb, outK, outV);
  attn_kernel<<<dim3(32, 32, 2), 256, 0, stream>>>(Qr, Kr, Vb, AttnB);
  gemm_bt<<<dim3(16, 32), 256, 0, stream>>>(AttnB, WoT, out, 4096, 2048, 2048);
}

// Round 3
// 264.192 us; speedup vs baseline: 1.8551x; 1.8551x over previous
//
#include <hip/hip_runtime.h>
#include <hip/hip_bf16.h>
#include <cstdint>

typedef uint16_t u16;
typedef __attribute__((ext_vector_type(8))) __bf16 bf16x8;
typedef __attribute__((ext_vector_type(4))) float f32x4;
typedef __attribute__((ext_vector_type(16))) float f32x16;
typedef __attribute__((ext_vector_type(8))) unsigned short u16x8;

#define GLD_LDS(SRC, DST) \
  __builtin_amdgcn_global_load_lds((const __attribute__((address_space(1))) void*)(SRC), \
                                   (__attribute__((address_space(3))) void*)(DST), 16, 0, 0)

__device__ __forceinline__ u16 f2bf(float f) {
  uint32_t u = __float_as_uint(f);
  u += 0x7fffu + ((u >> 16) & 1u);   // RNE; inputs are finite
  return (u16)(u >> 16);
}

__device__ __forceinline__ uint32_t pk2(float a, float b) {
  union { __bf16 h[2]; uint32_t u; } x;
  x.h[0] = (__bf16)a; x.h[1] = (__bf16)b;
  return x.u;
}

__device__ __forceinline__ float fexp2(float x) {
#if __has_builtin(__builtin_amdgcn_exp2f)
  return __builtin_amdgcn_exp2f(x);
#else
  return exp2f(x);
#endif
}

// ---------------- cast fp32 -> bf16, 4 elems/thread ----------------
__global__ void cast_f32_bf16(const float* __restrict__ in, u16* __restrict__ out, int n4) {
  int i = blockIdx.x * blockDim.x + threadIdx.x;
  if (i < n4) {
    const float4 v = reinterpret_cast<const float4*>(in)[i];
    ushort4 o;
    o.x = f2bf(v.x); o.y = f2bf(v.y); o.z = f2bf(v.z); o.w = f2bf(v.w);
    reinterpret_cast<ushort4*>(out)[i] = o;
  }
}

// ---------------- W[K][N] f32 -> Wt[N][K] bf16 ----------------
__global__ void transpose_cast(const float* __restrict__ W, u16* __restrict__ Wt, int K, int N) {
  __shared__ float tile[32][33];
  int n0 = blockIdx.x * 32, k0 = blockIdx.y * 32;
  int tx = threadIdx.x, ty = threadIdx.y;
  #pragma unroll
  for (int i = ty; i < 32; i += 8)
    tile[i][tx] = W[(size_t)(k0 + i) * N + n0 + tx];
  __syncthreads();
  #pragma unroll
  for (int i = ty; i < 32; i += 8)
    Wt[(size_t)(n0 + i) * K + k0 + tx] = f2bf(tile[tx][i]);
}

// ---------------- RoPE cos/sin tables [T][32] ----------------
__global__ void rope_tables_k(float* __restrict__ cosT, float* __restrict__ sinT) {
  int t = blockIdx.x, i = threadIdx.x;  // 32 threads
  float invf = powf(10000.0f, -(float)i * (1.0f / 32.0f));
  float ang = (float)t * invf;
  cosT[t * 32 + i] = cosf(ang);
  sinT[t * 32 + i] = sinf(ang);
}

// ---------------- GEMM: C[M][N] f32 = A[M][K]bf16 * Bt[N][K]bf16^T ----------------
__global__ __launch_bounds__(256) void gemm_bt(const u16* __restrict__ A, const u16* __restrict__ Bt,
                                               float* __restrict__ C, int M, int N, int K) {
  __shared__ alignas(16) u16 As[128 * 32];
  __shared__ alignas(16) u16 Bs[128 * 32];
  int tid = threadIdx.x;
  int l = tid & 63, w = tid >> 6;
  int l15 = l & 15, l4 = l >> 4;
  int wr = w >> 1, wc = w & 1;
  int m0 = blockIdx.y * 128, n0 = blockIdx.x * 128;

  f32x4 acc[4][4] = {};

  int srow = tid >> 2;
  int scol = (tid & 3) * 8;
  const u16* Ag = A + (size_t)(m0 + srow) * K + scol;
  const u16* Bg = Bt + (size_t)(n0 + srow) * K + scol;
  char* AsD = (char*)As + tid * 16;
  char* BsD = (char*)Bs + tid * 16;
  const size_t rowskip = (size_t)64 * K;

  for (int kt = 0; kt < K; kt += 32) {
    GLD_LDS(Ag + kt, AsD);
    GLD_LDS(Ag + kt + rowskip, AsD + 4096);
    GLD_LDS(Bg + kt, BsD);
    GLD_LDS(Bg + kt + rowskip, BsD + 4096);
    __syncthreads();
    bf16x8 af[4], bfr[4];
    #pragma unroll
    for (int m = 0; m < 4; ++m)
      af[m] = *reinterpret_cast<const bf16x8*>(&As[(wr * 64 + m * 16 + l15) * 32 + l4 * 8]);
    #pragma unroll
    for (int n = 0; n < 4; ++n)
      bfr[n] = *reinterpret_cast<const bf16x8*>(&Bs[(wc * 64 + n * 16 + l15) * 32 + l4 * 8]);
    #pragma unroll
    for (int m = 0; m < 4; ++m)
      #pragma unroll
      for (int n = 0; n < 4; ++n)
        acc[m][n] = __builtin_amdgcn_mfma_f32_16x16x32_bf16(af[m], bfr[n], acc[m][n], 0, 0, 0);
    __syncthreads();
  }
  #pragma unroll
  for (int m = 0; m < 4; ++m)
    #pragma unroll
    for (int n = 0; n < 4; ++n)
      #pragma unroll
      for (int r = 0; r < 4; ++r) {
        int row = m0 + wr * 64 + m * 16 + l4 * 4 + r;
        int col = n0 + wc * 64 + n * 16 + l15;
        C[(size_t)row * N + col] = acc[m][n][r];
      }
}

// ---------------- RoPE + scatter ----------------
// Qr pre-scaled by 0.125*log2(e) for exp2-domain softmax.
__global__ __launch_bounds__(256) void rope_scatter(const float* __restrict__ QKV,
    const float* __restrict__ cosT, const float* __restrict__ sinT,
    u16* __restrict__ Qr, u16* __restrict__ Kr,
    float* __restrict__ outK, float* __restrict__ outV) {
  const float QSCALE = 0.125f * 1.44269504088896f;
  int row = blockIdx.x;            // b*2048 + t
  int b = row >> 11, t = row & 2047;
  const float* src = QKV + (size_t)row * 3072;
  int tid = threadIdx.x;
  #pragma unroll
  for (int p = tid; p < 1024; p += 256) {
    int h = p >> 5, d = p & 31;
    float c = cosT[t * 32 + d], s = sinT[t * 32 + d];
    float q0 = src[h * 64 + d], q1 = src[h * 64 + d + 32];
    size_t base = ((size_t)(b * 32 + h) * 2048 + t) * 64 + d;
    Qr[base]      = f2bf((q0 * c - q1 * s) * QSCALE);
    Qr[base + 32] = f2bf((q1 * c + q0 * s) * QSCALE);
  }
  {
    int p = tid;                    // exactly 256 (g,d) pairs
    int gk = p >> 5, d = p & 31;
    float c = cosT[t * 32 + d], s = sinT[t * 32 + d];
    float k0 = src[2048 + gk * 64 + d], k1 = src[2048 + gk * 64 + d + 32];
    float r0 = k0 * c - k1 * s, r1 = k1 * c + k0 * s;
    size_t base = ((size_t)(b * 8 + gk) * 2048 + t) * 64 + d;
    Kr[base] = f2bf(r0); Kr[base + 32] = f2bf(r1);
    outK[base] = r0; outK[base + 32] = r1;
  }
  #pragma unroll
  for (int p = tid; p < 512; p += 256) {
    int gv = p >> 6, d = p & 63;
    size_t base = ((size_t)(b * 8 + gv) * 2048 + t) * 64 + d;
    outV[base] = src[2560 + gv * 64 + d];
  }
}

// ---------------- V transpose: outV f32 [bg][2048 t][64 d] -> Vt bf16 [bg][64 d][2048 t] ----------------
__global__ __launch_bounds__(256) void v_transpose(const float* __restrict__ src, u16* __restrict__ dst) {
  __shared__ float tile[64][65];
  int tt = blockIdx.x, bg = blockIdx.y;
  int tid = threadIdx.x;
  const float* sp = src + (size_t)bg * 2048 * 64 + (size_t)tt * 64 * 64;
  int tl = tid >> 2, c0 = (tid & 3) * 16;
  #pragma unroll
  for (int i = 0; i < 4; ++i) {
    float4 v = *reinterpret_cast<const float4*>(sp + (size_t)tl * 64 + c0 + i * 4);
    tile[tl][c0 + i * 4 + 0] = v.x;
    tile[tl][c0 + i * 4 + 1] = v.y;
    tile[tl][c0 + i * 4 + 2] = v.z;
    tile[tl][c0 + i * 4 + 3] = v.w;
  }
  __syncthreads();
  int d = tid >> 2, j0 = (tid & 3) * 16;
  u16x8 a, c;
  #pragma unroll
  for (int j = 0; j < 8; ++j) a[j] = f2bf(tile[j0 + j][d]);
  #pragma unroll
  for (int j = 0; j < 8; ++j) c[j] = f2bf(tile[j0 + 8 + j][d]);
  u16* dp = dst + (size_t)bg * 64 * 2048 + (size_t)d * 2048 + tt * 64 + j0;
  *reinterpret_cast<u16x8*>(dp) = a;
  *reinterpret_cast<u16x8*>(dp + 8) = c;
}

// ---------------- flash attention, swapped-operand 32x32x16, causal GQA ----------------
// grid 512 blocks (qc desc, g, b), 512 thr = 8 waves: (w&3)=head-in-group, (w>>2)=q-subtile.
// Per wave: 32 q rows; S^T = mfma(K,Q) -> lane q = l&31 holds P row (split with lane^32).
// O^T = mfma(V^T, P^T); P^T assembled in-register (pack + shfl_xor 32).
__global__ __launch_bounds__(512) void attn_kernel(
    const u16* __restrict__ Qr, const u16* __restrict__ Kr,
    const u16* __restrict__ Vt, u16* __restrict__ Ao) {
  __shared__ alignas(16) u16 Ks[64][72];   // [kv][d] pitch 72
  __shared__ alignas(16) u16 Vs[64][72];   // [d][kv] pitch 72

  int bid = blockIdx.x;
  int qc = 31 - (bid >> 4);
  int g = (bid >> 1) & 7;
  int b = bid & 1;
  int tid = threadIdx.x;
  int w = tid >> 6, l = tid & 63;
  int l31 = l & 31, hi = l >> 5;
  int h = g * 4 + (w & 3);
  int sub = w >> 2;
  int q0w = qc * 64 + sub * 32;

  const u16* Qh = Qr + ((size_t)(b * 32 + h) * 2048 + q0w) * 64;
  const u16* Kh = Kr + (size_t)(b * 8 + g) * 2048 * 64;
  const u16* Vh = Vt + (size_t)(b * 8 + g) * 64 * 2048;

  // Q fragments: lane l -> B[k=d][n=q]: Q[q0w+l31][16t + 8*hi .. +8]
  bf16x8 qf[4];
  #pragma unroll
  for (int t = 0; t < 4; ++t)
    qf[t] = *reinterpret_cast<const bf16x8*>(Qh + (size_t)l31 * 64 + t * 16 + hi * 8);

  f32x16 o0 = {}, o1 = {};
  float m = -INFINITY, lsum = 0.f;

  int srow = tid >> 3, sc = (tid & 7) * 8;
  const int qg = q0w + l31;

  for (int s = 0; s <= qc; ++s) {
    // stage K and V^T tiles (issue loads before barrier)
    bf16x8 kstage = *reinterpret_cast<const bf16x8*>(Kh + (size_t)(s * 64 + srow) * 64 + sc);
    bf16x8 vstage = *reinterpret_cast<const bf16x8*>(Vh + (size_t)srow * 2048 + s * 64 + sc);
    __syncthreads();
    *reinterpret_cast<bf16x8*>(&Ks[srow][sc]) = kstage;
    *reinterpret_cast<bf16x8*>(&Vs[srow][sc]) = vstage;
    __syncthreads();

    int nh = (s == qc && sub == 0) ? 1 : 2;   // diagonal: sub0's kv half1 fully masked
    f32x16 sacc[2];
    #pragma unroll
    for (int hf = 0; hf < 2; ++hf) {
      if (hf < nh) {
        f32x16 z = {};
        #pragma unroll
        for (int t = 0; t < 4; ++t) {
          bf16x8 kf = *reinterpret_cast<const bf16x8*>(&Ks[hf * 32 + l31][t * 16 + hi * 8]);
          z = __builtin_amdgcn_mfma_f32_32x32x16_bf16(kf, qf[t], z, 0, 0, 0);
        }
        sacc[hf] = z;
      }
    }
    if (s == qc) {
      #pragma unroll
      for (int hf = 0; hf < 2; ++hf)
        if (hf < nh) {
          #pragma unroll
          for (int r = 0; r < 16; ++r) {
            int kvg = s * 64 + hf * 32 + (r & 3) + (r >> 2) * 8 + hi * 4;
            if (kvg > qg) sacc[hf][r] = -INFINITY;
          }
        }
    }
    // online softmax: row state lives in lane pair (l, l^32), q = l31
    float pmax = sacc[0][0];
    #pragma unroll
    for (int r = 1; r < 16; ++r) pmax = fmaxf(pmax, sacc[0][r]);
    if (nh == 2) {
      #pragma unroll
      for (int r = 0; r < 16; ++r) pmax = fmaxf(pmax, sacc[1][r]);
    }
    pmax = fmaxf(pmax, __shfl_xor(pmax, 32));
    float mnew = fmaxf(m, pmax);
    float corr = fexp2(m - mnew);
    float p_[32];
    float psum = 0.f;
    #pragma unroll
    for (int hf = 0; hf < 2; ++hf) {
      if (hf < nh) {
        #pragma unroll
        for (int r = 0; r < 16; ++r) {
          float pv = fexp2(sacc[hf][r] - mnew);
          p_[hf * 16 + r] = pv;
          psum += pv;
        }
      }
    }
    psum += __shfl_xor(psum, 32);
    lsum = lsum * corr + psum;
    m = mnew;
    #pragma unroll
    for (int r = 0; r < 16; ++r) { o0[r] *= corr; o1[r] *= corr; }

    // pack P -> bf16 pairs; group gi covers kv = 8*gi + 4*hi + {0..3}
    uint32_t pkA[8], pkB[8];
    #pragma unroll
    for (int gi = 0; gi < 8; ++gi) {
      if (gi < nh * 4) {
        pkA[gi] = pk2(p_[gi * 4 + 0], p_[gi * 4 + 1]);
        pkB[gi] = pk2(p_[gi * 4 + 2], p_[gi * 4 + 3]);
      }
    }
    #pragma unroll
    for (int kc = 0; kc < 4; ++kc) {
      if (kc < nh * 2) {
        // exchange: send group (2kc + !hi), receive partner's; assemble B-frag kv=16kc+8hi+0..7
        uint32_t zA = pkA[kc * 2 + (hi ^ 1)];
        uint32_t zB = pkB[kc * 2 + (hi ^ 1)];
        uint32_t sA = (uint32_t)__shfl_xor((int)zA, 32);
        uint32_t sB = (uint32_t)__shfl_xor((int)zB, 32);
        uint32_t oA = pkA[kc * 2 + hi];
        uint32_t oB = pkB[kc * 2 + hi];
        union { uint32_t wd[4]; bf16x8 v; } pb;
        pb.wd[0] = hi ? sA : oA;
        pb.wd[1] = hi ? sB : oB;
        pb.wd[2] = hi ? oA : sA;
        pb.wd[3] = hi ? oB : sB;
        bf16x8 va0 = *reinterpret_cast<const bf16x8*>(&Vs[l31][kc * 16 + hi * 8]);
        bf16x8 va1 = *reinterpret_cast<const bf16x8*>(&Vs[32 + l31][kc * 16 + hi * 8]);
        o0 = __builtin_amdgcn_mfma_f32_32x32x16_bf16(va0, pb.v, o0, 0, 0, 0);
        o1 = __builtin_amdgcn_mfma_f32_32x32x16_bf16(va1, pb.v, o1, 0, 0, 0);
      }
    }
  }

  float inv = 1.0f / lsum;
  int token = b * 2048 + q0w + l31;
  u16* dst = Ao + (size_t)token * 2048 + h * 64;
  #pragma unroll
  for (int hf = 0; hf < 2; ++hf) {
    f32x16 ov = hf ? o1 : o0;
    #pragma unroll
    for (int r = 0; r < 16; r += 2) {
      int d = (r & 3) + (r >> 2) * 8 + hi * 4 + hf * 32;
      *reinterpret_cast<uint32_t*>(dst + d) = pk2(ov[r] * inv, ov[r + 1] * inv);
    }
  }
}

extern "C" void kernel_launch(void* const* d_in, const int* in_sizes, int n_in,
                              void* d_out, int out_size, void* d_ws, size_t ws_size,
                              hipStream_t stream) {
  const float* x  = (const float*)d_in[0];
  const float* Wq = (const float*)d_in[1];
  const float* Wk = (const float*)d_in[2];
  const float* Wv = (const float*)d_in[3];
  const float* Wo = (const float*)d_in[4];
  float* out = (float*)d_out;

  char* ws = (char*)d_ws;
  u16*   Xb    = (u16*)(ws + 0);              // [4096][2048] bf16
  u16*   Wcat  = (u16*)(ws + 16777216);       // [3072][2048] bf16 = {Wq^T, Wk^T, Wv^T}
  u16*   WoT   = (u16*)(ws + 29360128);       // [2048][2048] bf16
  float* QKV   = (float*)(ws + 37748736);     // [4096][3072] f32
  u16*   AttnB = (u16*)(ws + 37748736);       // reuse after rope: [4096][2048] bf16
  u16*   Qr    = (u16*)(ws + 88080384);       // [2][32][2048][64] bf16 (pre-scaled, exp2 domain)
  u16*   Kr    = (u16*)(ws + 104857600);      // [2][8][2048][64] bf16
  u16*   Vtr   = (u16*)(ws + 109051904);      // [2][8][64][2048] bf16 (V transposed)
  float* cosT  = (float*)(ws + 113246208);    // [2048][32]
  float* sinT  = (float*)(ws + 113508352);    // [2048][32]

  float* outK = out + 8388608;
  float* outV = out + 10485760;

  cast_f32_bf16<<<8192, 256, 0, stream>>>(x, Xb, 2097152);
  transpose_cast<<<dim3(64, 64), dim3(32, 8), 0, stream>>>(Wq, Wcat, 2048, 2048);
  transpose_cast<<<dim3(16, 64), dim3(32, 8), 0, stream>>>(Wk, Wcat + 2048 * 2048, 2048, 512);
  transpose_cast<<<dim3(16, 64), dim3(32, 8), 0, stream>>>(Wv, Wcat + 2560 * 2048, 2048, 512);
  transpose_cast<<<dim3(64, 64), dim3(32, 8), 0, stream>>>(Wo, WoT, 2048, 2048);
  rope_tables_k<<<2048, 32, 0, stream>>>(cosT, sinT);
  gemm_bt<<<dim3(24, 32), 256, 0, stream>>>(Xb, Wcat, QKV, 4096, 3072, 2048);
  rope_scatter<<<4096, 256, 0, stream>>>(QKV, cosT, sinT, Qr, Kr, outK, outV);
  v_transpose<<<dim3(32, 16), 256, 0, stream>>>(outV, Vtr);
  attn_kernel<<<512, 512, 0, stream>>>(Qr, Kr, Vtr, AttnB);
  gemm_bt<<<dim3(16, 32), 256, 0, stream>>>(AttnB, WoT, out, 4096, 2048, 2048);
}